// Round 13
// baseline (175.965 us; speedup 1.0000x reference)
//
#include <hip/hip_runtime.h>
#include <hip/hip_bf16.h>

typedef __attribute__((ext_vector_type(8))) short bf16x8;
typedef __attribute__((ext_vector_type(4))) float f32x4;

#define GRU_B 131072
#define BM 32
#define TPB 4                        // row-tiles per persistent block
#define NBLK (GRU_B / (BM * TPB))    // 1024 blocks -> ~4/CU queued, 3 resident

static __device__ __forceinline__ ushort f2bf(float f) {
  union { float f; unsigned u; } v; v.f = f;
  unsigned r = v.u + 0x7FFFu + ((v.u >> 16) & 1u);   // RNE
  return (ushort)(r >> 16);
}
static __device__ __forceinline__ float bf2f(ushort u) {
  union { unsigned u; float f; } v; v.u = ((unsigned)u) << 16;
  return v.f;
}
static __device__ __forceinline__ unsigned pk2(float a, float b) {
  float2 t; t.x = a; t.y = b;
  __hip_bfloat162 r = __float22bfloat162_rn(t);      // v_cvt_pk_bf16_f32
  union { __hip_bfloat162 b; unsigned u; } cv; cv.b = r;
  return cv.u;
}
static __device__ __forceinline__ float fsig(float x) {
  return __builtin_amdgcn_rcpf(1.0f + __expf(-x));
}
static __device__ __forceinline__ float ftanh(float x) {
  return 1.0f - 2.0f * __builtin_amdgcn_rcpf(1.0f + __expf(2.0f * x));
}
static __device__ __forceinline__ f32x4 splat4(float s) {
  f32x4 v = {s, s, s, s}; return v;
}
// two-bit XOR swizzle: b128 row reads 2-way (free), column gathers 2-way
static __device__ __forceinline__ int swz(int row, int cbyte) {
  return (row * 256 + cbyte) ^ ((row & 7) << 4) ^ ((row & 8) << 2);
}

// Raw barrier: LDS visibility only — NO vmcnt drain, prefetch loads survive.
#define BARRIER() do {                                       \
  asm volatile("s_waitcnt lgkmcnt(0)" ::: "memory");         \
  __builtin_amdgcn_s_barrier();                              \
  asm volatile("" ::: "memory");                             \
} while (0)

// Pack six 128x128 fp32 weight matrices into per-lane MFMA B-fragment order:
// chunk = ((mat*8 + cb)*4 + kb), 1KB each; within chunk lane*16B holds
// w[kb*32 + (lane>>4)*8 + e][cb*16 + (lane&15)], e=0..7, bf16.
__global__ void wtrans_kernel(const float* __restrict__ wz, const float* __restrict__ uz,
                              const float* __restrict__ wr, const float* __restrict__ ur,
                              const float* __restrict__ wh, const float* __restrict__ uh,
                              ushort* __restrict__ outw) {
  int f = blockIdx.x * 256 + threadIdx.x;          // 0..98303 (coalesced write)
  int mat = f >> 14;
  int rem = f & 16383;
  int chunk = rem >> 9;                            // 0..31
  int lane = (rem >> 3) & 63;
  int e = rem & 7;
  int cb = chunk >> 2, k0b = chunk & 3;
  int n = cb * 16 + (lane & 15);
  int k = k0b * 32 + (lane >> 4) * 8 + e;
  const float* src = (mat == 0) ? wz : (mat == 1) ? uz : (mat == 2) ? wr
                   : (mat == 3) ? ur : (mat == 4) ? wh : uh;
  outw[f] = f2bf(src[k * 128 + n]);
}

#define MFMA __builtin_amdgcn_mfma_f32_16x16x32_bf16

__global__ __launch_bounds__(512, 6) void gru_kernel(
    const float* __restrict__ x, const float* __restrict__ hprev,
    const ushort* __restrict__ wt,
    const float* __restrict__ bz, const float* __restrict__ br,
    const float* __restrict__ bh, float* __restrict__ out) {
  // 48 KB: S[i] = i*16K (xs +0, hs +8K) double-buffered; RH[r] = 32K + r*8K
  __shared__ __align__(16) char smem[49152];

  const int tid = threadIdx.x;
  const int lane = tid & 63;
  const int wid = tid >> 6;          // 8 waves: 16 output cols each
  const int l15 = lane & 15;
  const int q = lane >> 4;
  const int n0 = wid * 16;

  const float brv = br[n0 + l15];
  const float bzv = bz[n0 + l15];
  const float bhv = bh[n0 + l15];

  // stream pass-1 weights from L2; hoist ONLY Uh (pass 2 is barrier-adjacent)
  const ushort* wlane = wt + (lane << 3);
  auto wfrag = [&](int mat, int kb) -> const bf16x8* {
    return (const bf16x8*)(wlane + ((((mat << 3) + wid) << 2) + kb) * 512);
  };
  bf16x8 Uh[4];
#pragma unroll
  for (int kb = 0; kb < 4; ++kb) Uh[kb] = *wfrag(5, kb);

  auto ldsA = [&](const char* base, int mr, int k0) -> bf16x8 {
    int row = mr * 16 + l15;
    return *(const bf16x8*)(base + swz(row, (k0 + q * 8) * 2));
  };

  const long tile0 = (long)blockIdx.x * TPB;
  const float4* xg = (const float4*)x;
  const float4* hg = (const float4*)hprev;

  // staging offsets (lane-constant)
  const int r0 = tid >> 5, cb0 = (tid & 31) << 3;
  const int bo0 = swz(r0, cb0), bo1 = swz(r0 + 16, cb0);

  auto stage = [&](char* S, const float4& a0, const float4& a1,
                   const float4& b0, const float4& b1) {
    uint2 v;
    v.x = pk2(a0.x, a0.y); v.y = pk2(a0.z, a0.w); *(uint2*)(S + bo0) = v;
    v.x = pk2(a1.x, a1.y); v.y = pk2(a1.z, a1.w); *(uint2*)(S + bo1) = v;
    v.x = pk2(b0.x, b0.y); v.y = pk2(b0.z, b0.w); *(uint2*)(S + 8192 + bo0) = v;
    v.x = pk2(b1.x, b1.y); v.y = pk2(b1.z, b1.w); *(uint2*)(S + 8192 + bo1) = v;
  };

  // -------- prologue: stage tile0, load tile1 regs --------
  float4 px0, px1, ph0, ph1;
  {
    long toff = tile0 * 1024;       // float4 index of tile 0
    px0 = xg[toff + tid]; px1 = xg[toff + 512 + tid];
    ph0 = hg[toff + tid]; ph1 = hg[toff + 512 + tid];
    stage(smem, px0, px1, ph0, ph1);
    if (TPB > 1) {
      toff += 1024;
      px0 = xg[toff + tid]; px1 = xg[toff + 512 + tid];
      ph0 = hg[toff + tid]; ph1 = hg[toff + 512 + tid];
    }
  }
  BARRIER();

  for (int t = 0; t < TPB; ++t) {
    char* Scur = smem + (t & 1) * 16384;
    char* RHc  = smem + 32768 + (t & 1) * 8192;
    const long row0 = (tile0 + t) * BM;

    // ---- stage tile t+1 from regs (dbuf-safe: writes S[(t+1)&1] != S[t&1],
    //      and any iter-(t-1) reader of S[(t+1)&1] is behind bar(t-1)) ----
    if (t + 1 < TPB) stage(smem + ((t + 1) & 1) * 16384, px0, px1, ph0, ph1);

    // ---- issue tile t+2 loads (raw barrier below won't drain them) ----
    if (t + 2 < TPB) {
      long toff = (tile0 + t + 2) * 1024;
      px0 = xg[toff + tid]; px1 = xg[toff + 512 + tid];
      ph0 = hg[toff + tid]; ph1 = hg[toff + 512 + tid];
    }

    // ---- pass 1 (weights streamed from L2 per kb, 40 MFMAs of cover):
    //      accr = x@Wr + h@Ur + br ; accz = x@Wz + h@Uz + bz ; acch = x@Wh + bh
    f32x4 accr[2], accz[2], acch[2];
    accr[0] = splat4(brv); accr[1] = splat4(brv);
    accz[0] = splat4(bzv); accz[1] = splat4(bzv);
    acch[0] = splat4(bhv); acch[1] = splat4(bhv);
    __builtin_amdgcn_s_setprio(1);
#pragma unroll
    for (int kb = 0; kb < 4; ++kb) {
      bf16x8 bWz = *wfrag(0, kb);
      bf16x8 bUz = *wfrag(1, kb);
      bf16x8 bWr = *wfrag(2, kb);
      bf16x8 bUr = *wfrag(3, kb);
      bf16x8 bWh = *wfrag(4, kb);
#pragma unroll
      for (int mr = 0; mr < 2; ++mr) {
        bf16x8 ax = ldsA(Scur, mr, kb * 32);
        bf16x8 ah = ldsA(Scur + 8192, mr, kb * 32);
        accr[mr] = MFMA(ax, bWr, accr[mr], 0, 0, 0);
        accr[mr] = MFMA(ah, bUr, accr[mr], 0, 0, 0);
        accz[mr] = MFMA(ax, bWz, accz[mr], 0, 0, 0);
        accz[mr] = MFMA(ah, bUz, accz[mr], 0, 0, 0);
        acch[mr] = MFMA(ax, bWh, acch[mr], 0, 0, 0);
      }
    }
    __builtin_amdgcn_s_setprio(0);

    // ---- rh = sigmoid(accr)*hp -> RH; cache hp in regs for the epilogue ----
    float hpv[2][4];
#pragma unroll
    for (int mr = 0; mr < 2; ++mr)
#pragma unroll
      for (int j = 0; j < 4; ++j) {
        int row = mr * 16 + q * 4 + j;
        int bo = swz(row, (n0 + l15) * 2);
        float hp = bf2f(*(const ushort*)(Scur + 8192 + bo));
        hpv[mr][j] = hp;
        *(ushort*)(RHc + bo) = f2bf(fsig(accr[mr][j]) * hp);
      }

    BARRIER();   // the ONLY barrier: rh visible, next-S staged; vmcnt survives

    // ---- pass 2: acch += rh @ Uh (Uh reg-resident — no naked L2 latency) ----
    __builtin_amdgcn_s_setprio(1);
#pragma unroll
    for (int kb = 0; kb < 4; ++kb)
#pragma unroll
      for (int mr = 0; mr < 2; ++mr)
        acch[mr] = MFMA(ldsA(RHc, mr, kb * 32), Uh[kb], acch[mr], 0, 0, 0);
    __builtin_amdgcn_s_setprio(0);

    // ---- epilogue: h_t = hp + z*(hc - hp) (hp from regs) ----
#pragma unroll
    for (int mr = 0; mr < 2; ++mr)
#pragma unroll
      for (int j = 0; j < 4; ++j) {
        int row = mr * 16 + q * 4 + j;
        float hc = ftanh(acch[mr][j]);
        float zv = fsig(accz[mr][j]);
        float hp = hpv[mr][j];
        out[(row0 + row) * 128 + n0 + l15] = hp + zv * (hc - hp);
      }
    // no trailing barrier: dbuf S/RH make it unnecessary (see stage comment)
  }
}

extern "C" void kernel_launch(void* const* d_in, const int* in_sizes, int n_in,
                              void* d_out, int out_size, void* d_ws, size_t ws_size,
                              hipStream_t stream) {
  const float* x  = (const float*)d_in[0];
  const float* h  = (const float*)d_in[1];
  const float* Wz = (const float*)d_in[2];
  const float* Uz = (const float*)d_in[3];
  const float* bz = (const float*)d_in[4];
  const float* Wr = (const float*)d_in[5];
  const float* Ur = (const float*)d_in[6];
  const float* br = (const float*)d_in[7];
  const float* Wh = (const float*)d_in[8];
  const float* Uh = (const float*)d_in[9];
  const float* bh = (const float*)d_in[10];
  ushort* wt = (ushort*)d_ws;   // 98304 bf16 = 192 KB packed fragment order

  hipLaunchKernelGGL(wtrans_kernel, dim3(384), dim3(256), 0, stream,
                     Wz, Uz, Wr, Ur, Wh, Uh, wt);
  hipLaunchKernelGGL(gru_kernel, dim3(NBLK), dim3(512), 0, stream,
                     x, h, wt, bz, br, bh, (float*)d_out);
}

// Round 14
// 52.791 us; speedup vs baseline: 3.3332x; 3.3332x over previous
//
#include <hip/hip_runtime.h>
#include <hip/hip_bf16.h>

typedef __attribute__((ext_vector_type(8))) short bf16x8;
typedef __attribute__((ext_vector_type(4))) float f32x4;

#define GRU_B 131072
#define BM 32
#define TPB 8                        // row-tiles per persistent block
#define NBLK (GRU_B / (BM * TPB))    // 512 blocks

static __device__ __forceinline__ ushort f2bf(float f) {
  union { float f; unsigned u; } v; v.f = f;
  unsigned r = v.u + 0x7FFFu + ((v.u >> 16) & 1u);   // RNE
  return (ushort)(r >> 16);
}
static __device__ __forceinline__ float bf2f(ushort u) {
  union { unsigned u; float f; } v; v.u = ((unsigned)u) << 16;
  return v.f;
}
static __device__ __forceinline__ unsigned pk2(float a, float b) {
  float2 t; t.x = a; t.y = b;
  __hip_bfloat162 r = __float22bfloat162_rn(t);      // v_cvt_pk_bf16_f32
  union { __hip_bfloat162 b; unsigned u; } cv; cv.b = r;
  return cv.u;
}
static __device__ __forceinline__ float fsig(float x) {
  return __builtin_amdgcn_rcpf(1.0f + __expf(-x));
}
static __device__ __forceinline__ float ftanh(float x) {
  return 1.0f - 2.0f * __builtin_amdgcn_rcpf(1.0f + __expf(2.0f * x));
}
// two-bit XOR swizzle: b128 row reads 2-way (free), b64 row-gathers conflict-free
static __device__ __forceinline__ int swz(int row, int cbyte) {
  return (row * 256 + cbyte) ^ ((row & 7) << 4) ^ ((row & 8) << 2);
}

// Raw barrier: LDS visibility only — NO vmcnt drain, prefetch loads survive.
#define BARRIER() do {                                       \
  asm volatile("s_waitcnt lgkmcnt(0)" ::: "memory");         \
  __builtin_amdgcn_s_barrier();                              \
  asm volatile("" ::: "memory");                             \
} while (0)

// Pack six 128x128 fp32 weight matrices into per-lane MFMA fragment order:
// chunk = ((mat*8 + cb)*4 + kb), 1KB each; within chunk lane*16B holds
// w[kb*32 + (lane>>4)*8 + e][cb*16 + (lane&15)], e=0..7, bf16.
// This is simultaneously a B-frag of W and an A-frag of W^T (lane-symmetric).
__global__ void wtrans_kernel(const float* __restrict__ wz, const float* __restrict__ uz,
                              const float* __restrict__ wr, const float* __restrict__ ur,
                              const float* __restrict__ wh, const float* __restrict__ uh,
                              ushort* __restrict__ outw) {
  int f = blockIdx.x * 256 + threadIdx.x;          // 0..98303 (coalesced write)
  int mat = f >> 14;
  int rem = f & 16383;
  int chunk = rem >> 9;                            // 0..31
  int lane = (rem >> 3) & 63;
  int e = rem & 7;
  int cb = chunk >> 2, k0b = chunk & 3;
  int n = cb * 16 + (lane & 15);
  int k = k0b * 32 + (lane >> 4) * 8 + e;
  const float* src = (mat == 0) ? wz : (mat == 1) ? uz : (mat == 2) ? wr
                   : (mat == 3) ? ur : (mat == 4) ? wh : uh;
  outw[f] = f2bf(src[k * 128 + n]);
}

#define MFMA __builtin_amdgcn_mfma_f32_16x16x32_bf16

__global__ __launch_bounds__(512, 2) void gru_kernel(
    const float* __restrict__ x, const float* __restrict__ hprev,
    const ushort* __restrict__ wt,
    const float* __restrict__ bz, const float* __restrict__ br,
    const float* __restrict__ bh, float* __restrict__ out) {
  // 64 KB: S[i]=i*16K (xs +0, hs +8K) tri-buffered; RH[r]=48K + r*8K dbuf
  __shared__ __align__(16) char smem[65536];

  const int tid = threadIdx.x;
  const int lane = tid & 63;
  const int wid = tid >> 6;          // 8 waves: 16 output cols each
  const int l15 = lane & 15;
  const int q = lane >> 4;
  const int n0 = wid * 16;

  // SWAPPED output layout: lane holds (batch row m = mtile*16+l15,
  // hidden cols n = n0 + q*4 + j, j=0..3). Bias varies along j:
  const float4 brv = *(const float4*)(br + n0 + q * 4);
  const float4 bzv = *(const float4*)(bz + n0 + q * 4);
  const float4 bhv = *(const float4*)(bh + n0 + q * 4);
  const f32x4 brv4 = {brv.x, brv.y, brv.z, brv.w};
  const f32x4 bzv4 = {bzv.x, bzv.y, bzv.z, bzv.w};
  const f32x4 bhv4 = {bhv.x, bhv.y, bhv.z, bhv.w};

  // hoist all 24 weight fragments into registers (reused across 8 tiles)
  const ushort* wlane = wt + (lane << 3);
  bf16x8 W[6][4];
#pragma unroll
  for (int mat = 0; mat < 6; ++mat)
#pragma unroll
    for (int kb = 0; kb < 4; ++kb)
      W[mat][kb] = *(const bf16x8*)(wlane + ((((mat << 3) + wid) << 2) + kb) * 512);

  auto ldsA = [&](const char* base, int mr, int k0) -> bf16x8 {
    int row = mr * 16 + l15;
    return *(const bf16x8*)(base + swz(row, (k0 + q * 8) * 2));
  };

  const long tile0 = (long)blockIdx.x * TPB;
  const float4* xg = (const float4*)x;
  const float4* hg = (const float4*)hprev;

  // staging offsets (lane-constant)
  const int r0 = tid >> 5, cb0 = (tid & 31) << 3;
  const int bo0 = swz(r0, cb0), bo1 = swz(r0 + 16, cb0);
  // rh/hp wide-op offsets: row = mr*16 + l15, byte col = (n0 + q*4)*2
  const int go0 = swz(l15, (n0 + q * 4) * 2);
  const int go1 = swz(16 + l15, (n0 + q * 4) * 2);

  auto stage = [&](char* S, const float4& a0, const float4& a1,
                   const float4& b0, const float4& b1) {
    uint2 v;
    v.x = pk2(a0.x, a0.y); v.y = pk2(a0.z, a0.w); *(uint2*)(S + bo0) = v;
    v.x = pk2(a1.x, a1.y); v.y = pk2(a1.z, a1.w); *(uint2*)(S + bo1) = v;
    v.x = pk2(b0.x, b0.y); v.y = pk2(b0.z, b0.w); *(uint2*)(S + 8192 + bo0) = v;
    v.x = pk2(b1.x, b1.y); v.y = pk2(b1.z, b1.w); *(uint2*)(S + 8192 + bo1) = v;
  };

  // -------- prologue: stage tile0, load tile1 regs --------
  float4 px0, px1, ph0, ph1;
  {
    long toff = tile0 * 1024;       // float4 index of tile 0
    px0 = xg[toff + tid]; px1 = xg[toff + 512 + tid];
    ph0 = hg[toff + tid]; ph1 = hg[toff + 512 + tid];
    stage(smem, px0, px1, ph0, ph1);
    if (TPB > 1) {
      toff += 1024;
      px0 = xg[toff + tid]; px1 = xg[toff + 512 + tid];
      ph0 = hg[toff + tid]; ph1 = hg[toff + 512 + tid];
    }
  }
  BARRIER();

  for (int t = 0; t < TPB; ++t) {
    char* Scur = smem + (t % 3) * 16384;
    char* RHc  = smem + 49152 + (t & 1) * 8192;
    const long row0 = (tile0 + t) * BM;

    // ---- stage tile t+1 from regs ----
    if (t + 1 < TPB) stage(smem + ((t + 1) % 3) * 16384, px0, px1, ph0, ph1);

    // ---- issue tile t+2 loads (raw barrier below won't drain them) ----
    if (t + 2 < TPB) {
      long toff = (tile0 + t + 2) * 1024;
      px0 = xg[toff + tid]; px1 = xg[toff + 512 + tid];
      ph0 = hg[toff + tid]; ph1 = hg[toff + 512 + tid];
    }

    // ---- pass 1 SWAPPED: accT = W^T-frag x act-frag (C^T layout out) ----
    //      accr = (x@Wr + h@Ur + br)^T ; accz ; acch = (x@Wh + bh)^T
    f32x4 accr[2], accz[2], acch[2];
    accr[0] = brv4; accr[1] = brv4;
    accz[0] = bzv4; accz[1] = bzv4;
    acch[0] = bhv4; acch[1] = bhv4;
    __builtin_amdgcn_s_setprio(1);
#pragma unroll
    for (int kb = 0; kb < 4; ++kb)
#pragma unroll
      for (int mr = 0; mr < 2; ++mr) {
        bf16x8 ax = ldsA(Scur, mr, kb * 32);
        bf16x8 ah = ldsA(Scur + 8192, mr, kb * 32);
        accr[mr] = MFMA(W[2][kb], ax, accr[mr], 0, 0, 0);
        accr[mr] = MFMA(W[3][kb], ah, accr[mr], 0, 0, 0);
        accz[mr] = MFMA(W[0][kb], ax, accz[mr], 0, 0, 0);
        accz[mr] = MFMA(W[1][kb], ah, accz[mr], 0, 0, 0);
        acch[mr] = MFMA(W[4][kb], ax, acch[mr], 0, 0, 0);
      }
    __builtin_amdgcn_s_setprio(0);

    // ---- rh = sigmoid(accr)*hp -> RH, WIDE ops (b64), hp cached ----
    uint2 hpk[2];
#pragma unroll
    for (int mr = 0; mr < 2; ++mr) {
      int go = mr ? go1 : go0;
      uint2 hp4 = *(const uint2*)(Scur + 8192 + go);   // 4 bf16 hp
      hpk[mr] = hp4;
      float h0 = bf2f((ushort)(hp4.x & 0xffff)), h1 = bf2f((ushort)(hp4.x >> 16));
      float h2 = bf2f((ushort)(hp4.y & 0xffff)), h3 = bf2f((ushort)(hp4.y >> 16));
      uint2 w;
      w.x = pk2(fsig(accr[mr][0]) * h0, fsig(accr[mr][1]) * h1);
      w.y = pk2(fsig(accr[mr][2]) * h2, fsig(accr[mr][3]) * h3);
      *(uint2*)(RHc + go) = w;                         // 4 bf16 rh, one b64
    }

    BARRIER();   // the ONLY barrier: rh visible, next-S staged; vmcnt survives

    // ---- pass 2 SWAPPED: acch += Uh^T-frag x rh-frag (reads identical) ----
    __builtin_amdgcn_s_setprio(1);
#pragma unroll
    for (int kb = 0; kb < 4; ++kb)
#pragma unroll
      for (int mr = 0; mr < 2; ++mr)
        acch[mr] = MFMA(W[5][kb], ldsA(RHc, mr, kb * 32), acch[mr], 0, 0, 0);
    __builtin_amdgcn_s_setprio(0);

    // ---- epilogue: h_t = hp + z*(hc - hp); ONE float4 store per mr ----
#pragma unroll
    for (int mr = 0; mr < 2; ++mr) {
      float hpf[4];
      hpf[0] = bf2f((ushort)(hpk[mr].x & 0xffff));
      hpf[1] = bf2f((ushort)(hpk[mr].x >> 16));
      hpf[2] = bf2f((ushort)(hpk[mr].y & 0xffff));
      hpf[3] = bf2f((ushort)(hpk[mr].y >> 16));
      float4 v;
#pragma unroll
      for (int j = 0; j < 4; ++j) {
        float hc = ftanh(acch[mr][j]);
        float zv = fsig(accz[mr][j]);
        ((float*)&v)[j] = hpf[j] + zv * (hc - hpf[j]);
      }
      *(float4*)(out + (row0 + mr * 16 + l15) * 128 + n0 + q * 4) = v;
    }
    // no trailing barrier: tri-buffered S / dbuf RH make it unnecessary
  }
}

extern "C" void kernel_launch(void* const* d_in, const int* in_sizes, int n_in,
                              void* d_out, int out_size, void* d_ws, size_t ws_size,
                              hipStream_t stream) {
  const float* x  = (const float*)d_in[0];
  const float* h  = (const float*)d_in[1];
  const float* Wz = (const float*)d_in[2];
  const float* Uz = (const float*)d_in[3];
  const float* bz = (const float*)d_in[4];
  const float* Wr = (const float*)d_in[5];
  const float* Ur = (const float*)d_in[6];
  const float* br = (const float*)d_in[7];
  const float* Wh = (const float*)d_in[8];
  const float* Uh = (const float*)d_in[9];
  const float* bh = (const float*)d_in[10];
  ushort* wt = (ushort*)d_ws;   // 98304 bf16 = 192 KB packed fragment order

  hipLaunchKernelGGL(wtrans_kernel, dim3(384), dim3(256), 0, stream,
                     Wz, Uz, Wr, Ur, Wh, Uh, wt);
  hipLaunchKernelGGL(gru_kernel, dim3(NBLK), dim3(512), 0, stream,
                     x, h, wt, bz, br, bh, (float*)d_out);
}